// Round 3
// baseline (666.591 us; speedup 1.0000x reference)
//
#include <hip/hip_runtime.h>
#include <math.h>

// Problem constants (all compile-time from the reference)
#define NB      32      // NUM_BLOCKS = D_HEAD/3
#define NHEADS  8
#define DH      96
#define DT      64
#define HALFT   32
#define BB      2
#define TT      8
#define HH      64
#define WW      64

typedef float f32x4 __attribute__((ext_vector_type(4)));
typedef float f32x2 __attribute__((ext_vector_type(2)));

// ---------------------------------------------------------------------------
// Kernel 1: temporal embedding  temp[b*T+t][d] = emb @ Wt.T + bt
// ---------------------------------------------------------------------------
__global__ void temp_kernel(const float* __restrict__ time_pos,
                            const float* __restrict__ freq_temporal,
                            const float* __restrict__ Wt,
                            const float* __restrict__ bt,
                            float* __restrict__ temp) {
    const int row = blockIdx.x;       // 0..15  (b*T + t)
    const int d   = threadIdx.x;      // 0..95
    const float p = time_pos[row];
    const float* __restrict__ wrow = Wt + d * DT;
    float sum = bt[d];
    #pragma unroll
    for (int j = 0; j < HALFT; ++j) {
        float s, c;
        sincosf(p * freq_temporal[j], &s, &c);
        sum = fmaf(c, wrow[2 * j], sum);
        sum = fmaf(s, wrow[2 * j + 1], sum);
    }
    temp[row * DH + d] = sum;
}

// ---------------------------------------------------------------------------
// Kernel 2: spatio rotation + temporal add.
// v4: LDS-staged full coalescing. Lessons so far:
//   v0 (1 triple/thread, dwordx3 seamless): rope ~157us, 5.1 TB/s
//   v2 (4 triples/thread, NT stride-48 x4): WRITE_SIZE 1.92x -> RMW disaster
//   v3 (plain stride-48 x4): WRITE fixed, but ~172us — per-instruction
//       scatter costs 3x L2 sector requests/byte on BOTH load & store paths.
// v4 makes every global access a wave-contiguous dwordx4 (4KB/instr, full
// lines — same pattern as the 6.4TB/s fill kernels) and does the
// triple-alignment permutation in LDS:
//   global (linear x4) -> LDS -> own 12 floats (b128, stride-12-dword =
//   2-way/16-lane phase = free) -> rotate -> LDS in-place -> linear stores.
// Stores are nontemporal: every store instr covers full 64B lines (v2's
// partial-line hazard structurally gone) and output lines shouldn't evict
// L3-resident q/k input (FETCH was 340MB < 402 ideal).
// Thread g handles 4 consecutive triples: float offset = 12*g.
//   b4 = g&7, x=(g>>3)&63, y=(g>>9)&63, head=(g>>15)&7, t=(g>>18)&7, b=g>>21
// ---------------------------------------------------------------------------
__global__ __launch_bounds__(256) void rope_kernel(
        const float* __restrict__ q,
        const float* __restrict__ k,
        const float* __restrict__ spatial_pos,
        const float* __restrict__ freq_spatial,
        const float* __restrict__ temp,
        float* __restrict__ qo,
        float* __restrict__ ko) {
    __shared__ f32x4 lds4[768];                    // 12 KB: 3072 floats
    const int tid = threadIdx.x;
    const unsigned g = blockIdx.x * 256u + tid;    // 0 .. 2^22-1

    const int b4   = g & 7;
    const int x    = (g >> 3)  & 63;
    const int y    = (g >> 9)  & 63;
    const int head = (g >> 15) & 7;
    const int t    = (g >> 18) & 7;
    const int b    = (int)(g >> 21);

    const size_t base = (size_t)blockIdx.x * 3072u;   // chunk start (floats)

    // ---- broadcast tables & angles (independent of q/k payload) ----
    const int sp = ((b * HH + y) * WW + x) * 2;
    const f32x2 ll = *(const f32x2*)(spatial_pos + sp);
    const float lat = ll[0], lon = ll[1];

    const f32x4* __restrict__ fptr =
        (const f32x4*)(freq_spatial + head * 64 + b4 * 8);  // 32B-aligned
    const f32x4 f01 = fptr[0];    // fa0 fb0 fa1 fb1
    const f32x4 f23 = fptr[1];    // fa2 fb2 fa3 fb3

    float sA[4], cA[4], sB[4], cB[4];
    {
        const float fa[4] = { f01[0], f01[2], f23[0], f23[2] };
        const float fb[4] = { f01[1], f01[3], f23[1], f23[3] };
        #pragma unroll
        for (int r = 0; r < 4; ++r) {
            __sincosf(lon * fa[r], &sA[r], &cA[r]);   // |angle| < ~0.2
            __sincosf(lat * fb[r], &sB[r], &cB[r]);
        }
    }

    float tv[12];
    {
        const float* __restrict__ trow = temp + (b * TT + t) * DH + b4 * 12;
        const f32x4 t0 = ((const f32x4*)trow)[0];
        const f32x4 t1 = ((const f32x4*)trow)[1];
        const f32x4 t2 = ((const f32x4*)trow)[2];
        #pragma unroll
        for (int c = 0; c < 4; ++c) {
            tv[c] = t0[c]; tv[4 + c] = t1[c]; tv[8 + c] = t2[c];
        }
    }

    const float* __restrict__ srcs[2] = { q, k };
    float*       __restrict__ dsts[2] = { qo, ko };

    #pragma unroll
    for (int s = 0; s < 2; ++s) {
        // 1) wave-contiguous global loads (4KB/instr per wave)
        const f32x4* __restrict__ gp = (const f32x4*)(srcs[s] + base);
        const f32x4 st0 = gp[tid];
        const f32x4 st1 = gp[tid + 256];
        const f32x4 st2 = gp[tid + 512];

        if (s) __syncthreads();   // prev tensor's store-phase readers done

        lds4[tid]       = st0;
        lds4[tid + 256] = st1;
        lds4[tid + 512] = st2;
        __syncthreads();

        // 2) gather own 12 consecutive floats (4 triples) from LDS
        //    b128 at dword 12*tid: 2-way/16-lane-phase bank aliasing = free
        const f32x4 a0 = lds4[tid * 3];
        const f32x4 a1 = lds4[tid * 3 + 1];
        const f32x4 a2 = lds4[tid * 3 + 2];
        float xf[12];
        #pragma unroll
        for (int c = 0; c < 4; ++c) {
            xf[c] = a0[c]; xf[4 + c] = a1[c]; xf[8 + c] = a2[c];
        }

        // 3) rotate 4 triples + temporal add
        // o0 =  x0*cA + x1*sA
        // o1 =  cB*u + x2*sB      where u = x1*cA - x0*sA
        // o2 = -sB*u + x2*cB
        float xr[12];
        #pragma unroll
        for (int r = 0; r < 4; ++r) {
            const float x0 = xf[3 * r], x1 = xf[3 * r + 1], x2 = xf[3 * r + 2];
            const float u = x1 * cA[r] - x0 * sA[r];
            xr[3 * r]     = x0 * cA[r] + x1 * sA[r] + tv[3 * r];
            xr[3 * r + 1] = cB[r] * u + x2 * sB[r] + tv[3 * r + 1];
            xr[3 * r + 2] = -sB[r] * u + x2 * cB[r] + tv[3 * r + 2];
        }

        // 4) write back IN-PLACE (same addresses this thread just read —
        //    no cross-thread access between the surrounding barriers)
        f32x4 r0, r1, r2;
        #pragma unroll
        for (int c = 0; c < 4; ++c) {
            r0[c] = xr[c]; r1[c] = xr[4 + c]; r2[c] = xr[8 + c];
        }
        lds4[tid * 3]     = r0;
        lds4[tid * 3 + 1] = r1;
        lds4[tid * 3 + 2] = r2;
        __syncthreads();

        // 5) wave-contiguous nontemporal stores (full 64B lines per instr)
        f32x4* __restrict__ op = (f32x4*)(dsts[s] + base);
        __builtin_nontemporal_store(lds4[tid],       op + tid);
        __builtin_nontemporal_store(lds4[tid + 256], op + tid + 256);
        __builtin_nontemporal_store(lds4[tid + 512], op + tid + 512);
    }
}

// ---------------------------------------------------------------------------
extern "C" void kernel_launch(void* const* d_in, const int* in_sizes, int n_in,
                              void* d_out, int out_size, void* d_ws, size_t ws_size,
                              hipStream_t stream) {
    const float* q             = (const float*)d_in[0];
    const float* k             = (const float*)d_in[1];
    const float* spatial_pos   = (const float*)d_in[2];
    const float* time_pos      = (const float*)d_in[3];
    const float* freq_spatial  = (const float*)d_in[4];
    const float* freq_temporal = (const float*)d_in[5];
    const float* Wt            = (const float*)d_in[6];
    const float* bt            = (const float*)d_in[7];

    float* out  = (float*)d_out;
    float* temp = (float*)d_ws;                       // 16*96*4 = 6144 B

    temp_kernel<<<BB * TT, DH, 0, stream>>>(time_pos, freq_temporal, Wt, bt, temp);

    const unsigned n_groups = BB * TT * NHEADS * HH * WW * (NB / 4);  // 2^22
    const size_t per_tensor = (size_t)n_groups * 12u;                 // 50,331,648
    rope_kernel<<<n_groups / 256, 256, 0, stream>>>(
        q, k, spatial_pos, freq_spatial, temp, out, out + per_tensor);
}